// Round 1
// baseline (220.636 us; speedup 1.0000x reference)
//
#include <hip/hip_runtime.h>
#include <hip/hip_bf16.h>
#include <math.h>

// Problem constants
#define BB 2
#define SS 2048
#define DD 1024
#define HH 16
#define DHH 64
#define MM (BB * SS) // 4096

typedef float f32x4 __attribute__((ext_vector_type(4)));
typedef float f32x16 __attribute__((ext_vector_type(16)));
typedef __bf16 bf16x8 __attribute__((ext_vector_type(8)));

#define N_QKV ((size_t)MM * DD)
#define N_W   ((size_t)DD * DD)

// ---- fallback scratch (used only if ws_size is too small) -----------------
__device__ unsigned short g_X [3][N_QKV];   // bf16 activations
__device__ unsigned short g_Q [N_QKV];      // bf16 Q*0.125*log2e  [m][n]
__device__ unsigned short g_K [N_QKV];      // bf16 K        [m][n]
__device__ unsigned short g_Vt[N_QKV];      // bf16 V^T [b][h][dh][s]
__device__ unsigned short g_Wt[3][N_W];     // bf16 Wt[n][k]

// fp32 -> bf16 RNE
__device__ __forceinline__ unsigned short f2bu(float f) {
    unsigned u = __float_as_uint(f);
    unsigned r = u + 0x7FFFu + ((u >> 16) & 1u);
    return (unsigned short)(r >> 16);
}

union FragU { uint4 u; bf16x8 v; unsigned short s[8]; };
static __device__ __forceinline__ bf16x8 ldfrag(const unsigned short* p) {
    FragU f; f.u = *(const uint4*)p; return f.v;
}

// pack two f32 -> one u32 of 2xbf16 (native cvt; RNE)
static __device__ __forceinline__ unsigned pkbf(float a, float b) {
    union { __bf16 h[2]; unsigned u; } w;
    w.h[0] = (__bf16)a; w.h[1] = (__bf16)b;
    return w.u;
}

// ---------------------------------------------------------------------------
// Activations fp32 -> bf16, merged. Grid (4096, 3).
__global__ __launch_bounds__(256) void cvt3(
        const float* __restrict__ x0, const float* __restrict__ x1,
        const float* __restrict__ x2, unsigned short* __restrict__ X)
{
    const float* src = blockIdx.y == 0 ? x0 : (blockIdx.y == 1 ? x1 : x2);
    unsigned short* dst = X + (size_t)blockIdx.y * N_QKV;
    const size_t i = ((size_t)blockIdx.x * 256 + threadIdx.x) * 4;
    const float4 v = *(const float4*)(src + i);
    ushort4 s;
    s.x = f2bu(v.x); s.y = f2bu(v.y); s.z = f2bu(v.z); s.w = f2bu(v.w);
    *(ushort4*)(dst + i) = s;
}

// ---------------------------------------------------------------------------
// Wt[n][k] = bf16(W[k][n]), merged. Grid (16,16,3).
__global__ __launch_bounds__(256) void transpose_w3(
        const float* __restrict__ W0, const float* __restrict__ W1,
        const float* __restrict__ W2, unsigned short* __restrict__ Wt3)
{
    const float* W = blockIdx.z == 0 ? W0 : (blockIdx.z == 1 ? W1 : W2);
    unsigned short* Wt = Wt3 + (size_t)blockIdx.z * N_W;
    __shared__ float Ts[64][65];
    const int t = threadIdx.x;
    const int k0 = blockIdx.y * 64, n0 = blockIdx.x * 64;
#pragma unroll
    for (int i = 0; i < 16; ++i) {
        const int f = t + 256 * i, r = f >> 6, c = f & 63;
        Ts[r][c] = W[(size_t)(k0 + r) * DD + n0 + c];
    }
    __syncthreads();
#pragma unroll
    for (int i = 0; i < 16; ++i) {
        const int f = t + 256 * i, r = f >> 6, c = f & 63;
        Wt[(size_t)(n0 + r) * DD + k0 + c] = f2bu(Ts[c][r]);
    }
}

// ---------------------------------------------------------------------------
// Merged projection GEMM: z=0 Q (scale (1/8)*log2e so attn can use exp2),
// z=1 K, z=2 V^T. 128x128 tile, BK=64, scalar-register prefetch. Grid (8,32,3).
__global__ __launch_bounds__(256) void proj3(
        const unsigned short* __restrict__ X, const unsigned short* __restrict__ Wt3,
        const float* __restrict__ bq, const float* __restrict__ bk,
        const float* __restrict__ bv,
        unsigned short* __restrict__ Qp, unsigned short* __restrict__ Kp,
        unsigned short* __restrict__ Vtp)
{
    const int z = blockIdx.z;
    const unsigned short* xb = X   + (size_t)z * N_QKV;
    const unsigned short* Wt = Wt3 + (size_t)z * N_W;
    const float* bias = z == 0 ? bq : (z == 1 ? bk : bv);
    const float scale = z == 0 ? 0.18033688011112042f : 1.0f; // 0.125*log2(e)

    __shared__ unsigned short As[128][72];
    __shared__ unsigned short Bs[128][72];
    const int t = threadIdx.x, lane = t & 63, w = t >> 6;
    const int q = lane >> 4, li = lane & 15;
    const int wm = (w >> 1) * 64, wn = (w & 1) * 64;
    const int m0 = blockIdx.y * 128, n0 = blockIdx.x * 128;
    const int rs = t >> 3, cs = (t & 7) * 8;   // staging row/col

    f32x4 acc[4][4];
#pragma unroll
    for (int mt = 0; mt < 4; ++mt)
#pragma unroll
        for (int nt = 0; nt < 4; ++nt) acc[mt][nt] = (f32x4)0.f;

    uint4 pa0, pa1, pa2, pa3, pb0, pb1, pb2, pb3;
#define PROJ_LD(kk) \
    pa0 = *(const uint4*)(xb + (size_t)(m0 + rs      ) * DD + (kk) + cs); \
    pa1 = *(const uint4*)(xb + (size_t)(m0 + rs + 32 ) * DD + (kk) + cs); \
    pa2 = *(const uint4*)(xb + (size_t)(m0 + rs + 64 ) * DD + (kk) + cs); \
    pa3 = *(const uint4*)(xb + (size_t)(m0 + rs + 96 ) * DD + (kk) + cs); \
    pb0 = *(const uint4*)(Wt + (size_t)(n0 + rs      ) * DD + (kk) + cs); \
    pb1 = *(const uint4*)(Wt + (size_t)(n0 + rs + 32 ) * DD + (kk) + cs); \
    pb2 = *(const uint4*)(Wt + (size_t)(n0 + rs + 64 ) * DD + (kk) + cs); \
    pb3 = *(const uint4*)(Wt + (size_t)(n0 + rs + 96 ) * DD + (kk) + cs);

    PROJ_LD(0)

    for (int kk = 0; kk < DD; kk += 64) {
        *(uint4*)&As[rs     ][cs] = pa0;
        *(uint4*)&As[rs + 32][cs] = pa1;
        *(uint4*)&As[rs + 64][cs] = pa2;
        *(uint4*)&As[rs + 96][cs] = pa3;
        *(uint4*)&Bs[rs     ][cs] = pb0;
        *(uint4*)&Bs[rs + 32][cs] = pb1;
        *(uint4*)&Bs[rs + 64][cs] = pb2;
        *(uint4*)&Bs[rs + 96][cs] = pb3;
        __syncthreads();                       // tile visible
        if (kk + 64 < DD) { PROJ_LD(kk + 64) } // prefetch overlaps MFMA phase
#pragma unroll
        for (int ks = 0; ks < 64; ks += 32) {
            bf16x8 a[4], b[4];
#pragma unroll
            for (int mt = 0; mt < 4; ++mt) a[mt] = ldfrag(&As[wm + mt * 16 + li][ks + q * 8]);
#pragma unroll
            for (int nt = 0; nt < 4; ++nt) b[nt] = ldfrag(&Bs[wn + nt * 16 + li][ks + q * 8]);
#pragma unroll
            for (int mt = 0; mt < 4; ++mt)
#pragma unroll
                for (int nt = 0; nt < 4; ++nt)
                    acc[mt][nt] = __builtin_amdgcn_mfma_f32_16x16x32_bf16(
                        a[mt], b[nt], acc[mt][nt], 0, 0, 0);
        }
        __syncthreads();                       // reads done before overwrite
    }
#undef PROJ_LD

    float bvv[4];
#pragma unroll
    for (int nt = 0; nt < 4; ++nt) bvv[nt] = bias[n0 + wn + nt * 16 + li];

    if (z < 2) {
        unsigned short* out = z == 0 ? Qp : Kp;
#pragma unroll
        for (int mt = 0; mt < 4; ++mt)
#pragma unroll
            for (int nt = 0; nt < 4; ++nt)
#pragma unroll
                for (int reg = 0; reg < 4; ++reg) {
                    const int m = m0 + wm + mt * 16 + q * 4 + reg;
                    out[(size_t)m * DD + n0 + wn + nt * 16 + li] =
                        f2bu((acc[mt][nt][reg] + bvv[nt]) * scale);
                }
    } else {
        const int b = m0 >> 11;          // 128-row m-tiles never cross batch
        const int h = (n0 + wn) >> 6;    // 64-wide wave n-slice == one head
#pragma unroll
        for (int mt = 0; mt < 4; ++mt)
#pragma unroll
            for (int nt = 0; nt < 4; ++nt) {
                const int s = (m0 & (SS - 1)) + wm + mt * 16 + q * 4;
                const int dh = nt * 16 + li;
                ushort4 sv;
                sv.x = f2bu(acc[mt][nt][0] + bvv[nt]);
                sv.y = f2bu(acc[mt][nt][1] + bvv[nt]);
                sv.z = f2bu(acc[mt][nt][2] + bvv[nt]);
                sv.w = f2bu(acc[mt][nt][3] + bvv[nt]);
                *(ushort4*)(Vtp + ((size_t)((b * HH + h) * DHH + dh)) * SS + s) = sv;
            }
    }
}

// ---------------------------------------------------------------------------
// attn5: swapped-operand 32x32x16 flash attention (T12/m214 structure).
//   - mfma(K,Q) -> S^T: lane owns q-col (lane&31), 16 regs = k rows
//     crow(r,hi) = (r&3) + 8*(r>>2) + 4*hi
//   - softmax fully in registers: exp2 (Q pre-scaled by 0.125*log2e), pack to
//     bf16 pairs, 2x shfl_xor(32) per kslot rebuilds the PV A-fragment.
//     No P LDS round-trip, no ones-MFMA (l is a free f32 running sum).
//   - K/V tiles XOR-swizzled (slot ^= row&7): stride-128B frag reads are
//     bank-minimal.
//   - double-buffered K/V, ONE barrier per 64-k tile; loads issued at loop
//     top, ds_write after QK^T+exp (T14 issue-early/write-late).
// Grid (16,16,2), 256 threads (4 waves x 32 q-rows).
__global__ __launch_bounds__(256) void attn5(
        const unsigned short* __restrict__ Qg, const unsigned short* __restrict__ Kg,
        const unsigned short* __restrict__ Vtg,
        const float* __restrict__ queries, float* __restrict__ outp)
{
    __shared__ unsigned short Kb[2][64][64];
    __shared__ unsigned short Vb[2][64][64];
    __shared__ float invL[4][32];

    const int t = threadIdx.x, lane = t & 63, w = t >> 6;
    const int col = lane & 31;          // q-row (QK) / dh (PV) owned by lane
    const int hi  = lane >> 5;
    const int qt = blockIdx.x, h = blockIdx.y, b = blockIdx.z;

    const int sr = t >> 3;              // staging row 0..31
    const int sc = t & 7;               // staging 16B slot

    const unsigned short* Kbase = Kg  + (size_t)(b * SS) * DD + h * DHH;
    const unsigned short* Vbase = Vtg + ((size_t)((b * HH + h) * DHH)) * SS;

    // Q fragments: lane holds Q[q = qt*128 + w*32 + col][d = i*16 + hi*8 + j]
    bf16x8 qa[4];
    {
        const unsigned short* qp =
            Qg + (size_t)(b * SS + qt * 128 + w * 32 + col) * DD + h * DHH + hi * 8;
#pragma unroll
        for (int i = 0; i < 4; ++i) qa[i] = ldfrag(qp + i * 16);
    }

    f32x16 o0 = (f32x16)0.f, o1 = (f32x16)0.f;
    float lsum = 0.f;

    uint4 k0, k1, v0, v1;
#define LD_TILE(s0) \
    k0 = *(const uint4*)(Kbase + (size_t)((s0) + sr     ) * DD + sc * 8); \
    k1 = *(const uint4*)(Kbase + (size_t)((s0) + sr + 32) * DD + sc * 8); \
    v0 = *(const uint4*)(Vbase + (size_t)(sr     ) * SS + (s0) + sc * 8); \
    v1 = *(const uint4*)(Vbase + (size_t)(sr + 32) * SS + (s0) + sc * 8);

#define ST_TILE(buf) \
    *(uint4*)&Kb[buf][sr     ][(sc ^ (sr & 7)) * 8] = k0; \
    *(uint4*)&Kb[buf][sr + 32][(sc ^ (sr & 7)) * 8] = k1; \
    *(uint4*)&Vb[buf][sr     ][(sc ^ (sr & 7)) * 8] = v0; \
    *(uint4*)&Vb[buf][sr + 32][(sc ^ (sr & 7)) * 8] = v1;

    LD_TILE(0)
    ST_TILE(0)
    __syncthreads();

    const int NT = SS / 64;
    for (int kt = 0; kt < NT; ++kt) {
        const int cur = kt & 1;
        if (kt + 1 < NT) { LD_TILE((kt + 1) * 64) }   // issue early (T14)

#pragma unroll
        for (int ksub = 0; ksub < 2; ++ksub) {
            // S^T = K Q^T : D[row=k][col=q], 4 chained d-slots
            f32x16 st = (f32x16)0.f;
            const int krow = ksub * 32 + col;
#pragma unroll
            for (int i = 0; i < 4; ++i) {
                bf16x8 ka = ldfrag(&Kb[cur][krow][((i * 2 + hi) ^ (krow & 7)) * 8]);
                st = __builtin_amdgcn_mfma_f32_32x32x16_bf16(ka, qa[i], st, 0, 0, 0);
            }

            // P = exp2(S^T') in registers; l running sum
            float pe[16];
#pragma unroll
            for (int r = 0; r < 16; ++r) { pe[r] = exp2f(st[r]); lsum += pe[r]; }

            // pack pairs: wl = regs 8s+0..3 (hi'=0 k-range), wh = regs 8s+4..7
            unsigned wl[2][2], wh[2][2];
#pragma unroll
            for (int s = 0; s < 2; ++s) {
                wl[s][0] = pkbf(pe[8 * s + 0], pe[8 * s + 1]);
                wl[s][1] = pkbf(pe[8 * s + 2], pe[8 * s + 3]);
                wh[s][0] = pkbf(pe[8 * s + 4], pe[8 * s + 5]);
                wh[s][1] = pkbf(pe[8 * s + 6], pe[8 * s + 7]);
            }

            // write-late staging: prev readers passed last barrier, loads aged
            if (ksub == 0 && kt + 1 < NT) { ST_TILE(cur ^ 1) }

            // build PV A-frags (k = ksub*32 + s*16 + hi*8 + j) and accumulate
#pragma unroll
            for (int s = 0; s < 2; ++s) {
                const unsigned self0 = hi ? wh[s][0] : wl[s][0];
                const unsigned self1 = hi ? wh[s][1] : wl[s][1];
                const unsigned send0 = hi ? wl[s][0] : wh[s][0];
                const unsigned send1 = hi ? wl[s][1] : wh[s][1];
                const unsigned r0 = (unsigned)__shfl_xor((int)send0, 32);
                const unsigned r1 = (unsigned)__shfl_xor((int)send1, 32);
                FragU pf;
                pf.u.x = hi ? r0 : self0;
                pf.u.y = hi ? r1 : self1;
                pf.u.z = hi ? self0 : r0;
                pf.u.w = hi ? self1 : r1;

                const int vslot = ksub * 4 + s * 2 + hi;
                bf16x8 vb0 = ldfrag(&Vb[cur][col     ][(vslot ^ (col & 7)) * 8]);
                bf16x8 vb1 = ldfrag(&Vb[cur][col + 32][(vslot ^ (col & 7)) * 8]);
                o0 = __builtin_amdgcn_mfma_f32_32x32x16_bf16(pf.v, vb0, o0, 0, 0, 0);
                o1 = __builtin_amdgcn_mfma_f32_32x32x16_bf16(pf.v, vb1, o1, 0, 0, 0);
            }
        }
        __syncthreads();               // tile cur fully consumed; cur^1 ready
    }
#undef LD_TILE
#undef ST_TILE

    // l: combine the two half-lane partial sums; broadcast 1/l via LDS
    const float lt = lsum + __shfl_xor(lsum, 32);
    if (lane < 32) invL[w][lane] = 1.f / lt;
    __syncthreads();

    // epilogue: rows = crow(reg,hi), cols = lane&31 (+32 for o1)
    const size_t gbase = (size_t)(b * SS + qt * 128 + w * 32) * DD + h * DHH + col;
#pragma unroll
    for (int reg = 0; reg < 16; ++reg) {
        const int rl = (reg & 3) + 8 * (reg >> 2) + 4 * hi;
        const float inv = invL[w][rl];
        const size_t g = gbase + (size_t)rl * DD;
        outp[g]      = o0[reg] * inv + queries[g];
        outp[g + 32] = o1[reg] * inv + queries[g + 32];
    }
}

// ---------------------------------------------------------------------------
extern "C" void kernel_launch(void* const* d_in, const int* in_sizes, int n_in,
                              void* d_out, int out_size, void* d_ws, size_t ws_size,
                              hipStream_t stream) {
    const float* queries = (const float*)d_in[0];
    const float* keys    = (const float*)d_in[1];
    const float* values  = (const float*)d_in[2];
    const float* Wq      = (const float*)d_in[3];
    const float* bq      = (const float*)d_in[4];
    const float* Wk      = (const float*)d_in[5];
    const float* bk      = (const float*)d_in[6];
    const float* Wv      = (const float*)d_in[7];
    const float* bv      = (const float*)d_in[8];
    float* outp = (float*)d_out;

    // scratch: prefer d_ws (54 MB needed); fall back to device globals.
    const size_t need = (6 * N_QKV + 3 * N_W) * sizeof(unsigned short);
    unsigned short *Xp, *Qp, *Kp, *Vtp, *Wtp;
    if (ws_size >= need) {
        Xp  = (unsigned short*)d_ws;
        Qp  = Xp + 3 * N_QKV;
        Kp  = Qp + N_QKV;
        Vtp = Kp + N_QKV;
        Wtp = Vtp + N_QKV;
    } else {
        hipGetSymbolAddress((void**)&Xp,  HIP_SYMBOL(g_X));
        hipGetSymbolAddress((void**)&Qp,  HIP_SYMBOL(g_Q));
        hipGetSymbolAddress((void**)&Kp,  HIP_SYMBOL(g_K));
        hipGetSymbolAddress((void**)&Vtp, HIP_SYMBOL(g_Vt));
        hipGetSymbolAddress((void**)&Wtp, HIP_SYMBOL(g_Wt));
    }

    const dim3 bp(256);
    cvt3<<<dim3(MM * DD / 1024, 3), bp, 0, stream>>>(queries, keys, values, Xp);
    transpose_w3<<<dim3(16, 16, 3), bp, 0, stream>>>(Wq, Wk, Wv, Wtp);
    proj3<<<dim3(8, 32, 3), bp, 0, stream>>>(Xp, Wtp, bq, bk, bv, Qp, Kp, Vtp);
    attn5<<<dim3(SS / 128, HH, BB), bp, 0, stream>>>(Qp, Kp, Vtp, queries, outp);
}

// Round 3
// 205.894 us; speedup vs baseline: 1.0716x; 1.0716x over previous
//
#include <hip/hip_runtime.h>
#include <hip/hip_bf16.h>
#include <math.h>

// Problem constants
#define BB 2
#define SS 2048
#define DD 1024
#define HH 16
#define DHH 64
#define MM (BB * SS) // 4096

typedef float f32x4 __attribute__((ext_vector_type(4)));
typedef float f32x16 __attribute__((ext_vector_type(16)));
typedef __bf16 bf16x8 __attribute__((ext_vector_type(8)));
typedef unsigned int u32x2 __attribute__((ext_vector_type(2)));

#define N_QKV ((size_t)MM * DD)
#define N_W   ((size_t)DD * DD)

// ---- fallback scratch (used only if ws_size is too small) -----------------
__device__ unsigned short g_X [3][N_QKV];   // bf16 activations
__device__ unsigned short g_Q [N_QKV];      // bf16 Q*0.125*log2e  [m][n]
__device__ unsigned short g_K [N_QKV];      // bf16 K        [m][n]
__device__ unsigned short g_Vt[N_QKV];      // bf16 V^T [b][h][dh][s]
__device__ unsigned short g_Wt[3][N_W];     // bf16 Wt[n][k]

// fp32 -> bf16 RNE
__device__ __forceinline__ unsigned short f2bu(float f) {
    unsigned u = __float_as_uint(f);
    unsigned r = u + 0x7FFFu + ((u >> 16) & 1u);
    return (unsigned short)(r >> 16);
}

union FragU { uint4 u; bf16x8 v; unsigned short s[8]; };
static __device__ __forceinline__ bf16x8 ldfrag(const unsigned short* p) {
    FragU f; f.u = *(const uint4*)p; return f.v;
}

// pack two f32 -> one u32 of 2xbf16 (compiler emits v_cvt_pk_bf16_f32)
static __device__ __forceinline__ unsigned pkbf(float a, float b) {
    union { __bf16 h[2]; unsigned u; } w;
    w.h[0] = (__bf16)a; w.h[1] = (__bf16)b;
    return w.u;
}

// raw v_exp_f32 (arg already in log2 domain; ocml exp2f adds range-fixup VALU)
static __device__ __forceinline__ float fexp2(float x) {
#if __has_builtin(__builtin_amdgcn_exp2f)
    return __builtin_amdgcn_exp2f(x);
#else
    return __expf(x * 0.6931471805599453f); // native exp path
#endif
}

// lane[i] <-> lane[i+32] half-exchange producing BOTH PV A-frag words.
// ISA: rows 2-3 (lanes 32-63) of VDST swap with rows 0-1 (lanes 0-31) of VSRC:
//   new_a = lane<32 ? own_a      : partner_b
//   new_b = lane<32 ? partner_a  : own_b
static __device__ __forceinline__ void plswap(unsigned &a, unsigned &b) {
#if __has_builtin(__builtin_amdgcn_permlane32_swap)
    u32x2 r = __builtin_amdgcn_permlane32_swap((int)a, (int)b, false, false);
    a = r[0]; b = r[1];
#else
    const bool hi = (threadIdx.x & 63) >= 32;
    unsigned x = hi ? a : b;                       // hi sends a(wl), lo sends b(wh)
    unsigned y = (unsigned)__shfl_xor((int)x, 32); // partner's sent word
    unsigned na = hi ? y : a;
    unsigned nb = hi ? b : y;
    a = na; b = nb;
#endif
}

// ---------------------------------------------------------------------------
// Activations fp32 -> bf16, merged. Grid (4096, 3).
__global__ __launch_bounds__(256) void cvt3(
        const float* __restrict__ x0, const float* __restrict__ x1,
        const float* __restrict__ x2, unsigned short* __restrict__ X)
{
    const float* src = blockIdx.y == 0 ? x0 : (blockIdx.y == 1 ? x1 : x2);
    unsigned short* dst = X + (size_t)blockIdx.y * N_QKV;
    const size_t i = ((size_t)blockIdx.x * 256 + threadIdx.x) * 4;
    const float4 v = *(const float4*)(src + i);
    ushort4 s;
    s.x = f2bu(v.x); s.y = f2bu(v.y); s.z = f2bu(v.z); s.w = f2bu(v.w);
    *(ushort4*)(dst + i) = s;
}

// ---------------------------------------------------------------------------
// Wt[n][k] = bf16(W[k][n]), merged. Grid (16,16,3).
__global__ __launch_bounds__(256) void transpose_w3(
        const float* __restrict__ W0, const float* __restrict__ W1,
        const float* __restrict__ W2, unsigned short* __restrict__ Wt3)
{
    const float* W = blockIdx.z == 0 ? W0 : (blockIdx.z == 1 ? W1 : W2);
    unsigned short* Wt = Wt3 + (size_t)blockIdx.z * N_W;
    __shared__ float Ts[64][65];
    const int t = threadIdx.x;
    const int k0 = blockIdx.y * 64, n0 = blockIdx.x * 64;
#pragma unroll
    for (int i = 0; i < 16; ++i) {
        const int f = t + 256 * i, r = f >> 6, c = f & 63;
        Ts[r][c] = W[(size_t)(k0 + r) * DD + n0 + c];
    }
    __syncthreads();
#pragma unroll
    for (int i = 0; i < 16; ++i) {
        const int f = t + 256 * i, r = f >> 6, c = f & 63;
        Wt[(size_t)(n0 + r) * DD + k0 + c] = f2bu(Ts[c][r]);
    }
}

// ---------------------------------------------------------------------------
// Merged projection GEMM: z=0 Q (scale (1/8)*log2e so attn can use exp2),
// z=1 K, z=2 V^T. 128x128 tile, BK=64, scalar-register prefetch. Grid (8,32,3).
__global__ __launch_bounds__(256) void proj3(
        const unsigned short* __restrict__ X, const unsigned short* __restrict__ Wt3,
        const float* __restrict__ bq, const float* __restrict__ bk,
        const float* __restrict__ bv,
        unsigned short* __restrict__ Qp, unsigned short* __restrict__ Kp,
        unsigned short* __restrict__ Vtp)
{
    const int z = blockIdx.z;
    const unsigned short* xb = X   + (size_t)z * N_QKV;
    const unsigned short* Wt = Wt3 + (size_t)z * N_W;
    const float* bias = z == 0 ? bq : (z == 1 ? bk : bv);
    const float scale = z == 0 ? 0.18033688011112042f : 1.0f; // 0.125*log2(e)

    __shared__ unsigned short As[128][72];
    __shared__ unsigned short Bs[128][72];
    const int t = threadIdx.x, lane = t & 63, w = t >> 6;
    const int q = lane >> 4, li = lane & 15;
    const int wm = (w >> 1) * 64, wn = (w & 1) * 64;
    const int m0 = blockIdx.y * 128, n0 = blockIdx.x * 128;
    const int rs = t >> 3, cs = (t & 7) * 8;   // staging row/col

    f32x4 acc[4][4];
#pragma unroll
    for (int mt = 0; mt < 4; ++mt)
#pragma unroll
        for (int nt = 0; nt < 4; ++nt) acc[mt][nt] = (f32x4)0.f;

    uint4 pa0, pa1, pa2, pa3, pb0, pb1, pb2, pb3;
#define PROJ_LD(kk) \
    pa0 = *(const uint4*)(xb + (size_t)(m0 + rs      ) * DD + (kk) + cs); \
    pa1 = *(const uint4*)(xb + (size_t)(m0 + rs + 32 ) * DD + (kk) + cs); \
    pa2 = *(const uint4*)(xb + (size_t)(m0 + rs + 64 ) * DD + (kk) + cs); \
    pa3 = *(const uint4*)(xb + (size_t)(m0 + rs + 96 ) * DD + (kk) + cs); \
    pb0 = *(const uint4*)(Wt + (size_t)(n0 + rs      ) * DD + (kk) + cs); \
    pb1 = *(const uint4*)(Wt + (size_t)(n0 + rs + 32 ) * DD + (kk) + cs); \
    pb2 = *(const uint4*)(Wt + (size_t)(n0 + rs + 64 ) * DD + (kk) + cs); \
    pb3 = *(const uint4*)(Wt + (size_t)(n0 + rs + 96 ) * DD + (kk) + cs);

    PROJ_LD(0)

    for (int kk = 0; kk < DD; kk += 64) {
        *(uint4*)&As[rs     ][cs] = pa0;
        *(uint4*)&As[rs + 32][cs] = pa1;
        *(uint4*)&As[rs + 64][cs] = pa2;
        *(uint4*)&As[rs + 96][cs] = pa3;
        *(uint4*)&Bs[rs     ][cs] = pb0;
        *(uint4*)&Bs[rs + 32][cs] = pb1;
        *(uint4*)&Bs[rs + 64][cs] = pb2;
        *(uint4*)&Bs[rs + 96][cs] = pb3;
        __syncthreads();                       // tile visible
        if (kk + 64 < DD) { PROJ_LD(kk + 64) } // prefetch overlaps MFMA phase
#pragma unroll
        for (int ks = 0; ks < 64; ks += 32) {
            bf16x8 a[4], b[4];
#pragma unroll
            for (int mt = 0; mt < 4; ++mt) a[mt] = ldfrag(&As[wm + mt * 16 + li][ks + q * 8]);
#pragma unroll
            for (int nt = 0; nt < 4; ++nt) b[nt] = ldfrag(&Bs[wn + nt * 16 + li][ks + q * 8]);
#pragma unroll
            for (int mt = 0; mt < 4; ++mt)
#pragma unroll
                for (int nt = 0; nt < 4; ++nt)
                    acc[mt][nt] = __builtin_amdgcn_mfma_f32_16x16x32_bf16(
                        a[mt], b[nt], acc[mt][nt], 0, 0, 0);
        }
        __syncthreads();                       // reads done before overwrite
    }
#undef PROJ_LD

    float bvv[4];
#pragma unroll
    for (int nt = 0; nt < 4; ++nt) bvv[nt] = bias[n0 + wn + nt * 16 + li];

    if (z < 2) {
        unsigned short* out = z == 0 ? Qp : Kp;
#pragma unroll
        for (int mt = 0; mt < 4; ++mt)
#pragma unroll
            for (int nt = 0; nt < 4; ++nt)
#pragma unroll
                for (int reg = 0; reg < 4; ++reg) {
                    const int m = m0 + wm + mt * 16 + q * 4 + reg;
                    out[(size_t)m * DD + n0 + wn + nt * 16 + li] =
                        f2bu((acc[mt][nt][reg] + bvv[nt]) * scale);
                }
    } else {
        const int b = m0 >> 11;          // 128-row m-tiles never cross batch
        const int h = (n0 + wn) >> 6;    // 64-wide wave n-slice == one head
#pragma unroll
        for (int mt = 0; mt < 4; ++mt)
#pragma unroll
            for (int nt = 0; nt < 4; ++nt) {
                const int s = (m0 & (SS - 1)) + wm + mt * 16 + q * 4;
                const int dh = nt * 16 + li;
                ushort4 sv;
                sv.x = f2bu(acc[mt][nt][0] + bvv[nt]);
                sv.y = f2bu(acc[mt][nt][1] + bvv[nt]);
                sv.z = f2bu(acc[mt][nt][2] + bvv[nt]);
                sv.w = f2bu(acc[mt][nt][3] + bvv[nt]);
                *(ushort4*)(Vtp + ((size_t)((b * HH + h) * DHH + dh)) * SS + s) = sv;
            }
    }
}

// ---------------------------------------------------------------------------
// attn6: swapped-operand 32x32x16 flash attention, VALU-lean.
//   vs attn5 (82.9us, VALUBusy 58%, conflicts 4.19M):
//   - raw v_exp_f32 (__builtin_amdgcn_exp2f) instead of ocml exp2f
//   - permlane32_swap builds PV A-frags: 1 VALU op/word-pair, replaces
//     ds_bpermute (the 4.19M conflict source) + ~48 cndmask/kt
//   - ILP: both 4-chain QK MFMAs (k rows 0-31 / 32-63) interleaved,
//     then all exps, then 4 independent PV chunks (o0/o1 2-way chains)
//   - #pragma unroll 2 on kt: 'cur' compile-time -> swizzled LDS addresses
//     fully loop-invariant
// Grid (16,16,2), 256 threads (4 waves x 32 q-rows).
__global__ __launch_bounds__(256) void attn6(
        const unsigned short* __restrict__ Qg, const unsigned short* __restrict__ Kg,
        const unsigned short* __restrict__ Vtg,
        const float* __restrict__ queries, float* __restrict__ outp)
{
    __shared__ unsigned short Kb[2][64][64];
    __shared__ unsigned short Vb[2][64][64];
    __shared__ float invL[4][32];

    const int t = threadIdx.x, lane = t & 63, w = t >> 6;
    const int col = lane & 31;          // q-row (QK) / dh (PV) owned by lane
    const int hi  = lane >> 5;
    const int qt = blockIdx.x, h = blockIdx.y, b = blockIdx.z;

    const int sr = t >> 3;              // staging row 0..31
    const int sc = t & 7;               // staging 16B slot

    const unsigned short* Kbase = Kg  + (size_t)(b * SS) * DD + h * DHH;
    const unsigned short* Vbase = Vtg + ((size_t)((b * HH + h) * DHH)) * SS;

    // Q fragments: lane holds Q[q = qt*128 + w*32 + col][d = i*16 + hi*8 + j]
    bf16x8 qa[4];
    {
        const unsigned short* qp =
            Qg + (size_t)(b * SS + qt * 128 + w * 32 + col) * DD + h * DHH + hi * 8;
#pragma unroll
        for (int i = 0; i < 4; ++i) qa[i] = ldfrag(qp + i * 16);
    }

    f32x16 o0 = (f32x16)0.f, o1 = (f32x16)0.f;
    float lsum = 0.f;
    const int xr = col & 7;             // read-side swizzle key (same for col+32)

    uint4 k0, k1, v0, v1;
#define LD_TILE(s0) \
    k0 = *(const uint4*)(Kbase + (size_t)((s0) + sr     ) * DD + sc * 8); \
    k1 = *(const uint4*)(Kbase + (size_t)((s0) + sr + 32) * DD + sc * 8); \
    v0 = *(const uint4*)(Vbase + (size_t)(sr     ) * SS + (s0) + sc * 8); \
    v1 = *(const uint4*)(Vbase + (size_t)(sr + 32) * SS + (s0) + sc * 8);

#define ST_TILE(buf) \
    *(uint4*)&Kb[buf][sr     ][(sc ^ (sr & 7)) * 8] = k0; \
    *(uint4*)&Kb[buf][sr + 32][(sc ^ (sr & 7)) * 8] = k1; \
    *(uint4*)&Vb[buf][sr     ][(sc ^ (sr & 7)) * 8] = v0; \
    *(uint4*)&Vb[buf][sr + 32][(sc ^ (sr & 7)) * 8] = v1;

    LD_TILE(0)
    ST_TILE(0)
    __syncthreads();

    const int NT = SS / 64;
#pragma unroll 2
    for (int kt = 0; kt < NT; ++kt) {
        const int cur = kt & 1;
        if (kt + 1 < NT) { LD_TILE((kt + 1) * 64) }   // issue early (T14)

        // S^T = K Q^T : two independent 4-chains (k rows 0-31, 32-63)
        f32x16 st0 = (f32x16)0.f, st1 = (f32x16)0.f;
#pragma unroll
        for (int i = 0; i < 4; ++i) {
            const int slot = ((i * 2 + hi) ^ xr) * 8;
            bf16x8 ka0 = ldfrag(&Kb[cur][col     ][slot]);
            bf16x8 ka1 = ldfrag(&Kb[cur][col + 32][slot]);
            st0 = __builtin_amdgcn_mfma_f32_32x32x16_bf16(ka0, qa[i], st0, 0, 0, 0);
            st1 = __builtin_amdgcn_mfma_f32_32x32x16_bf16(ka1, qa[i], st1, 0, 0, 0);
        }

        // P = exp2(S^T) in regs; pack to bf16 pairs.
        // pkw[c]: c = 16-k chunk (c0,c1 from st0; c2,c3 from st1)
        // [0]=wl0 [1]=wl1 (this lane's k-low quad) [2]=wh0 [3]=wh1 (k-high quad)
        unsigned pkw[4][4];
        {
            float pe0[16], pe1[16];
#pragma unroll
            for (int r = 0; r < 16; ++r) { pe0[r] = fexp2(st0[r]); }
#pragma unroll
            for (int r = 0; r < 16; ++r) { pe1[r] = fexp2(st1[r]); }
            float ls = 0.f;
#pragma unroll
            for (int r = 0; r < 16; ++r) ls += pe0[r] + pe1[r];
            lsum += ls;
#pragma unroll
            for (int s = 0; s < 2; ++s) {
                pkw[s][0]     = pkbf(pe0[8 * s + 0], pe0[8 * s + 1]);
                pkw[s][1]     = pkbf(pe0[8 * s + 2], pe0[8 * s + 3]);
                pkw[s][2]     = pkbf(pe0[8 * s + 4], pe0[8 * s + 5]);
                pkw[s][3]     = pkbf(pe0[8 * s + 6], pe0[8 * s + 7]);
                pkw[2 + s][0] = pkbf(pe1[8 * s + 0], pe1[8 * s + 1]);
                pkw[2 + s][1] = pkbf(pe1[8 * s + 2], pe1[8 * s + 3]);
                pkw[2 + s][2] = pkbf(pe1[8 * s + 4], pe1[8 * s + 5]);
                pkw[2 + s][3] = pkbf(pe1[8 * s + 6], pe1[8 * s + 7]);
            }
        }

        // write-late staging (T14): prev readers passed the last barrier
        if (kt + 1 < NT) { ST_TILE(cur ^ 1) }

        // PV: per 16-k chunk, permlane32_swap yields words 0/2 (and 1/3)
#pragma unroll
        for (int c = 0; c < 4; ++c) {
            unsigned a0 = pkw[c][0], b0 = pkw[c][2];
            unsigned a1 = pkw[c][1], b1 = pkw[c][3];
            plswap(a0, b0);
            plswap(a1, b1);
            FragU pf;
            pf.u.x = a0; pf.u.y = a1; pf.u.z = b0; pf.u.w = b1;

            const int vs = ((c * 2 + hi) ^ xr) * 8;
            bf16x8 vb0 = ldfrag(&Vb[cur][col     ][vs]);
            bf16x8 vb1 = ldfrag(&Vb[cur][col + 32][vs]);
            o0 = __builtin_amdgcn_mfma_f32_32x32x16_bf16(pf.v, vb0, o0, 0, 0, 0);
            o1 = __builtin_amdgcn_mfma_f32_32x32x16_bf16(pf.v, vb1, o1, 0, 0, 0);
        }
        __syncthreads();               // tile cur fully consumed; cur^1 ready
    }
#undef LD_TILE
#undef ST_TILE

    // l: combine the two half-lane partial sums; broadcast 1/l via LDS
    const float lt = lsum + __shfl_xor(lsum, 32);
    if (lane < 32) invL[w][lane] = 1.f / lt;
    __syncthreads();

    // epilogue: rows = crow(reg,hi), cols = lane&31 (+32 for o1)
    const size_t gbase = (size_t)(b * SS + qt * 128 + w * 32) * DD + h * DHH + col;
#pragma unroll
    for (int reg = 0; reg < 16; ++reg) {
        const int rl = (reg & 3) + 8 * (reg >> 2) + 4 * hi;
        const float inv = invL[w][rl];
        const size_t g = gbase + (size_t)rl * DD;
        outp[g]      = o0[reg] * inv + queries[g];
        outp[g + 32] = o1[reg] * inv + queries[g + 32];
    }
}

// ---------------------------------------------------------------------------
extern "C" void kernel_launch(void* const* d_in, const int* in_sizes, int n_in,
                              void* d_out, int out_size, void* d_ws, size_t ws_size,
                              hipStream_t stream) {
    const float* queries = (const float*)d_in[0];
    const float* keys    = (const float*)d_in[1];
    const float* values  = (const float*)d_in[2];
    const float* Wq      = (const float*)d_in[3];
    const float* bq      = (const float*)d_in[4];
    const float* Wk      = (const float*)d_in[5];
    const float* bk      = (const float*)d_in[6];
    const float* Wv      = (const float*)d_in[7];
    const float* bv      = (const float*)d_in[8];
    float* outp = (float*)d_out;

    // scratch: prefer d_ws (54 MB needed); fall back to device globals.
    const size_t need = (6 * N_QKV + 3 * N_W) * sizeof(unsigned short);
    unsigned short *Xp, *Qp, *Kp, *Vtp, *Wtp;
    if (ws_size >= need) {
        Xp  = (unsigned short*)d_ws;
        Qp  = Xp + 3 * N_QKV;
        Kp  = Qp + N_QKV;
        Vtp = Kp + N_QKV;
        Wtp = Vtp + N_QKV;
    } else {
        hipGetSymbolAddress((void**)&Xp,  HIP_SYMBOL(g_X));
        hipGetSymbolAddress((void**)&Qp,  HIP_SYMBOL(g_Q));
        hipGetSymbolAddress((void**)&Kp,  HIP_SYMBOL(g_K));
        hipGetSymbolAddress((void**)&Vtp, HIP_SYMBOL(g_Vt));
        hipGetSymbolAddress((void**)&Wtp, HIP_SYMBOL(g_Wt));
    }

    const dim3 bp(256);
    cvt3<<<dim3(MM * DD / 1024, 3), bp, 0, stream>>>(queries, keys, values, Xp);
    transpose_w3<<<dim3(16, 16, 3), bp, 0, stream>>>(Wq, Wk, Wv, Wtp);
    proj3<<<dim3(8, 32, 3), bp, 0, stream>>>(Xp, Wtp, bq, bk, bv, Qp, Kp, Vtp);
    attn6<<<dim3(SS / 128, HH, BB), bp, 0, stream>>>(Qp, Kp, Vtp, queries, outp);
}